// Round 3
// baseline (231.021 us; speedup 1.0000x reference)
//
#include <hip/hip_runtime.h>
#include <stdint.h>
#include <math.h>

typedef unsigned int u32;
typedef unsigned long long u64;

#define E_CNT   8192
#define N_CNT   4096
#define TOT_N   (1u << 26)     // E*E elements, one threefry eval each (partitionable)
#define OUT_K   16384          // K*E = 2*8192
#define NODE_BM_WORDS 128      // 4096 bits / 32
#define N_CHUNKS 1024          // 2^26 bits / 2^16 bits-per-chunk

// ---- workspace layout (bytes) ----
#define OFF_BAD      0x000000  // u32[4096*128]   2 MiB  bad-bitmap per node
#define OFF_CNT_DST  0x200000  // u32[4096]
#define OFF_CNT_SRC  0x204000  // u32[4096]
#define OFF_CCOUNT   0x208000  // u32[1024] chunk keep-counts
#define OFF_SCALARS  0x209000  // [0]=num_neg, [1]=done ticket, [2]=T9 (threshold<<9)
#define OFF_KEEPBM   0x210000  // u64[1<<20]     8 MiB  keep bitmap
#define ZERO_BYTES   0x209040  // zero bad..scalars (keep_bm fully overwritten)

// rotl as a single v_alignbit_b32: alignbit(x,x,32-d) = (x>>(32-d))|(x<<d)
__device__ __forceinline__ u32 rotl32(u32 x, u32 d) {
  return __builtin_amdgcn_alignbit(x, x, 32u - d);
}

// FOUR interleaved JAX threefry2x32 evals, key=(0,42), counters (0,ia)..(0,id).
// Per-chain op sequence identical to the verified version (partitionable mode:
// per-element counter = (hi,lo) of flat index, bits = o0 ^ o1).
__device__ __forceinline__ void threefry4_0_42(u32 ia, u32 ib, u32 ic, u32 id,
                                               u32& ra, u32& rb, u32& rc, u32& rd) {
  const u32 k1 = 42u, k2 = 0x1BD11BF0u; // 0 ^ 42 ^ 0x1BD11BDA
  // Initial inject: x0 += k0(0) folds, x1 += k1. State (X0, X1) per chain.
  u32 A0 = 0u, A1 = ia + k1;
  u32 B0 = 0u, B1 = ib + k1;
  u32 C0 = 0u, C1 = ic + k1;
  u32 D0 = 0u, D1 = id + k1;
#define R4(r) { A0 += A1; B0 += B1; C0 += C1; D0 += D1; \
  A1 = rotl32(A1, r); B1 = rotl32(B1, r); C1 = rotl32(C1, r); D1 = rotl32(D1, r); \
  A1 ^= A0; B1 ^= B0; C1 ^= C0; D1 ^= D0; }
#define INJ(c0, c1) { A0 += (c0); B0 += (c0); C0 += (c0); D0 += (c0); \
  A1 += (c1); B1 += (c1); C1 += (c1); D1 += (c1); }
#define INJ1(c1) { A1 += (c1); B1 += (c1); C1 += (c1); D1 += (c1); }
  R4(13) R4(15) R4(26) R4(6)
  INJ(k1, k2 + 1u)
  R4(17) R4(29) R4(16) R4(24)
  INJ(k2, 2u)                    // k0+2 = 2
  R4(13) R4(15) R4(26) R4(6)
  INJ1(k1 + 3u)                  // A0 += k0(0) folds
  R4(17) R4(29) R4(16) R4(24)
  INJ(k1, k2 + 4u)
  R4(13) R4(15) R4(26) R4(6)
  INJ(k2, 5u)                    // k0+5 = 5
#undef R4
#undef INJ
#undef INJ1
  ra = A0 ^ A1;
  rb = B0 ^ B1;
  rc = C0 ^ C1;
  rd = D0 ^ D1;
}

// --- K1: bad bitmap + histograms + output padding prefill ---
__global__ void k_build(const int* __restrict__ src, const int* __restrict__ dst,
                        u32* __restrict__ bad, u32* __restrict__ cnt_dst,
                        u32* __restrict__ cnt_src, int* __restrict__ out) {
  int tid = blockIdx.x * 256 + threadIdx.x;   // < 8192
  if (tid < N_CNT) {
    atomicOr(&bad[(u32)tid * NODE_BM_WORDS + ((u32)tid >> 5)], 1u << (tid & 31));
  }
  u32 s = (u32)src[tid], d = (u32)dst[tid];
  atomicOr(&bad[s * NODE_BM_WORDS + (d >> 5)], 1u << (d & 31));
  atomicAdd(&cnt_dst[d], 1u);
  atomicAdd(&cnt_src[s], 1u);
  // prefill: nonzero fill_value=0 -> flat idx 0 -> (src[0], dst[0])
  int s0 = src[0], d0 = dst[0];
  out[tid] = s0;            out[tid + E_CNT] = s0;
  out[OUT_K + tid] = d0;    out[OUT_K + tid + E_CNT] = d0;
}

// --- K2: num_negatives + fused threshold epilogue (last-block-done) ---
// one row per wave (coalesced); block LDS reduce -> 256 atomics total
__global__ void __launch_bounds__(1024) k_rowcount(const u32* __restrict__ bad,
                                                   const u32* __restrict__ cnt_dst,
                                                   const u32* __restrict__ cnt_src,
                                                   u32* __restrict__ scal) {
  int wv = threadIdx.x >> 6, ln = threadIdx.x & 63;
  int n = blockIdx.x * 16 + wv;                 // 256 blocks x 16 waves = 4096 rows
  const u32* row = bad + (u32)n * NODE_BM_WORDS;
  u32 sum = 0;
#pragma unroll
  for (int h = 0; h < 2; ++h) {
    int w = ln + h * 64;
    u32 bits = row[w];
    while (bits) { int b = __ffs(bits) - 1; sum += cnt_dst[(w << 5) + b]; bits &= bits - 1; }
  }
#pragma unroll
  for (int off = 32; off > 0; off >>= 1) sum += __shfl_down(sum, off, 64);
  __shared__ u32 part[16];
  if (ln == 0) part[wv] = ((u32)E_CNT - sum) * cnt_src[n];
  __syncthreads();
  if (threadIdx.x == 0) {
    u32 tot = 0;
#pragma unroll
    for (int k = 0; k < 16; ++k) tot += part[k];
    atomicAdd(&scal[0], tot);
    __threadfence();
    if (atomicAdd(&scal[1], 1u) == 255u) {      // last of 256 blocks
      u32 nn = atomicAdd(&scal[0], 0u);         // coherent read
      u32 ratio = nn >> 13;                     // num_neg // E
      float kp = 2.0f / (float)ratio;           // f32(K)/f32(ratio), as JAX
      // u = m*2^-23 exact; u < kp  <=>  m < T = ceil(kp*2^23)  <=>  bits < T<<9
      u32 T = (u32)ceil((double)kp * 8388608.0);
      u32 T9 = (T >= (1u << 23)) ? 0xFFFFFFFFu : (T << 9);
      atomicExch(&scal[2], T9);
    }
  }
}

// --- K3: per-lane threefry, 64 consecutive elements/thread, own u64 word ---
// Removes ballots + serial lane-0 tail; grid 32768 -> 4096 blocks (dispatch cost).
// keep_bm layout unchanged: bit e of word[tid] = element tid*64 + e.
__global__ void __launch_bounds__(256) k_sample(const int* __restrict__ src,
                                                const int* __restrict__ dst,
                                                const u32* __restrict__ bad,
                                                const u32* __restrict__ scal,
                                                u64* __restrict__ keep_bm,
                                                u32* __restrict__ ccount) {
  u32 tid = blockIdx.x * 256u + threadIdx.x;    // < 1<<20
  u32 ebase = tid << 6;                         // 64 consecutive elements
  u32 T9 = scal[2];
  u32 whi = 0u, wlo = 0u;
  // MSB-first packing: insert element 63 first (w = w*2 + bit), so a rolled
  // loop works (no j-dependent masks). Elements 63..32 -> whi, 31..0 -> wlo.
#pragma unroll 2
  for (int j = 15; j >= 8; --j) {
    u32 i0 = ebase + 4u * (u32)j;
    u32 b0, b1, b2, b3;
    threefry4_0_42(i0, i0 + 1u, i0 + 2u, i0 + 3u, b0, b1, b2, b3);
    whi = whi + whi + (u32)(b3 < T9);
    whi = whi + whi + (u32)(b2 < T9);
    whi = whi + whi + (u32)(b1 < T9);
    whi = whi + whi + (u32)(b0 < T9);
  }
#pragma unroll 2
  for (int j = 7; j >= 0; --j) {
    u32 i0 = ebase + 4u * (u32)j;
    u32 b0, b1, b2, b3;
    threefry4_0_42(i0, i0 + 1u, i0 + 2u, i0 + 3u, b0, b1, b2, b3);
    wlo = wlo + wlo + (u32)(b3 < T9);
    wlo = wlo + wlo + (u32)(b2 < T9);
    wlo = wlo + wlo + (u32)(b1 < T9);
    wlo = wlo + wlo + (u32)(b0 < T9);
  }
  u64 w = ((u64)whi << 32) | (u64)wlo;
  if (w) {  // rare per-lane (~1.5% of lanes): refine kept bits against bad bitmap
    u64 rem = w;
    while (rem) {
      int b = __ffsll((unsigned long long)rem) - 1;
      u32 i = ebase + (u32)b;
      u32 n = (u32)src[i >> 13];
      u32 v = (u32)dst[i & 8191];
      if ((bad[n * NODE_BM_WORDS + (v >> 5)] >> (v & 31)) & 1u)
        w &= ~(1ull << b);
      rem &= rem - 1;
    }
  }
  keep_bm[tid] = w;                             // coalesced 8B/lane
  u32 c = (u32)__popcll(w);
#pragma unroll
  for (int off = 32; off > 0; off >>= 1) c += __shfl_down(c, off, 64);
  if ((threadIdx.x & 63u) == 0u && c)
    atomicAdd(&ccount[tid >> 10], c);           // chunk = 1024 threads, wave-uniform
}

// --- K4: ordered compaction; wave-shuffle scans (2 barriers, not 32) ---
__global__ void k_compact(const int* __restrict__ src, const int* __restrict__ dst,
                          const u64* __restrict__ keep_bm, const u32* __restrict__ ccount,
                          int* __restrict__ out) {
  int c = blockIdx.x;                       // chunk id, 1024 u64 words each
  int t = threadIdx.x;                      // 256 threads
  int wvid = t >> 6, ln = t & 63;
  __shared__ u32 red[4];                    // per-wave partial sums (chunk base)
  __shared__ u32 wsum[4];                   // per-wave scan totals (rank scan)

  // ---- chunk base: reduce ccount[0..c-1] (only a sum is needed, not a scan) ----
  u32 part = 0;
#pragma unroll
  for (int k = 0; k < 4; ++k) {
    int q = t + k * 256;                    // q < 1024, always in-bounds
    u32 vq = ccount[q];
    part += (q < c) ? vq : 0u;
  }
  u32 r = part;
#pragma unroll
  for (int off = 32; off > 0; off >>= 1) r += __shfl_down(r, off, 64);
  if (ln == 0) red[wvid] = r;

  // ---- local popcounts (overlap loads with the reduce above) ----
  const u64* words = keep_bm + (size_t)c * 1024;
  u64 w[4];
  u32 cnt = 0;
#pragma unroll
  for (int k = 0; k < 4; ++k) { w[k] = words[4 * t + k]; cnt += (u32)__popcll(w[k]); }

  // ---- rank scan: wave-level inclusive shuffle scan + cross-wave combine ----
  u32 scan = cnt;
#pragma unroll
  for (int off = 1; off < 64; off <<= 1) {
    u32 x = __shfl_up(scan, off, 64);
    if (ln >= off) scan += x;
  }
  if (ln == 63) wsum[wvid] = scan;
  __syncthreads();
  u32 coff_c = red[0] + red[1] + red[2] + red[3];
  u32 wbase = 0;
#pragma unroll
  for (int k = 0; k < 4; ++k) wbase += (k < wvid) ? wsum[k] : 0u;

  u32 rank = coff_c + wbase + scan - cnt;   // global rank of my first set bit
  u32 tbase = (u32)c * 65536u + (u32)t * 256u;
#pragma unroll
  for (int k = 0; k < 4; ++k) {
    u64 bits = w[k];
    while (bits) {
      int b = __ffsll((unsigned long long)bits) - 1;
      if (rank < OUT_K) {
        u32 tt = tbase + (u32)k * 64u + (u32)b;
        out[rank]         = src[tt >> 13];   // edge_src[rows]
        out[OUT_K + rank] = dst[tt & 8191];  // edge_dst[cols]
      }
      rank++;
      bits &= bits - 1;
    }
  }
}

extern "C" void kernel_launch(void* const* d_in, const int* in_sizes, int n_in,
                              void* d_out, int out_size, void* d_ws, size_t ws_size,
                              hipStream_t stream) {
  const int* src = (const int*)d_in[1];  // edge_src
  const int* dst = (const int*)d_in[2];  // edge_dst  (node_feature d_in[0] unused)
  int* out = (int*)d_out;                // [edge_src_neg(16384) | edge_dst_neg(16384)]
  char* ws = (char*)d_ws;

  u32* bad     = (u32*)(ws + OFF_BAD);
  u32* cnt_dst = (u32*)(ws + OFF_CNT_DST);
  u32* cnt_src = (u32*)(ws + OFF_CNT_SRC);
  u32* ccount  = (u32*)(ws + OFF_CCOUNT);
  u32* scal    = (u32*)(ws + OFF_SCALARS);
  u64* keep_bm = (u64*)(ws + OFF_KEEPBM);

  hipMemsetAsync(ws, 0, ZERO_BYTES, stream);
  k_build<<<E_CNT / 256, 256, 0, stream>>>(src, dst, bad, cnt_dst, cnt_src, out);
  k_rowcount<<<N_CNT / 16, 1024, 0, stream>>>(bad, cnt_dst, cnt_src, scal);
  k_sample<<<TOT_N / (256 * 64), 256, 0, stream>>>(src, dst, bad, scal, keep_bm, ccount);
  k_compact<<<N_CHUNKS, 256, 0, stream>>>(src, dst, keep_bm, ccount, out);
}

// Round 4
// 186.490 us; speedup vs baseline: 1.2388x; 1.2388x over previous
//
#include <hip/hip_runtime.h>
#include <stdint.h>
#include <math.h>

typedef unsigned int u32;
typedef unsigned long long u64;

#define E_CNT   8192
#define N_CNT   4096
#define TOT_N   (1u << 26)     // E*E elements, one threefry eval each (partitionable)
#define OUT_K   16384          // K*E = 2*8192
#define NODE_BM_WORDS 128      // 4096 bits / 32
#define N_CHUNKS 1024          // 2^26 bits / 2^16 bits-per-chunk

// ---- workspace layout (bytes) ----
#define OFF_BAD      0x000000  // u32[4096*128]   2 MiB  bad-bitmap per node
#define OFF_CNT_DST  0x200000  // u32[4096]
#define OFF_CNT_SRC  0x204000  // u32[4096]
#define OFF_CCOUNT   0x208000  // u32[1024] chunk keep-counts
#define OFF_SCALARS  0x209000  // [0]=num_neg, [1]=done ticket, [2]=T9 (threshold<<9)
#define OFF_KEEPBM   0x210000  // u64[1<<20]     8 MiB  keep bitmap
#define ZERO_BYTES   0x209040  // zero bad..scalars (keep_bm fully overwritten)

// rotl as a single v_alignbit_b32: alignbit(x,x,32-d) = (x>>(32-d))|(x<<d)
__device__ __forceinline__ u32 rotl32(u32 x, u32 d) {
  return __builtin_amdgcn_alignbit(x, x, 32u - d);
}

// FOUR interleaved JAX threefry2x32 evals, key=(0,42), counters (0,ia)..(0,id).
// Partitionable mode: per-element counter = flat index, bits = o0 ^ o1.
__device__ __forceinline__ void threefry4_0_42(u32 ia, u32 ib, u32 ic, u32 id,
                                               u32& ra, u32& rb, u32& rc, u32& rd) {
  const u32 k1 = 42u, k2 = 0x1BD11BF0u; // 0 ^ 42 ^ 0x1BD11BDA
  // Initial inject: x0 += k0(0) folds, x1 += k1. State (X0, X1) per chain.
  u32 A0 = 0u, A1 = ia + k1;
  u32 B0 = 0u, B1 = ib + k1;
  u32 C0 = 0u, C1 = ic + k1;
  u32 D0 = 0u, D1 = id + k1;
#define R4(r) { A0 += A1; B0 += B1; C0 += C1; D0 += D1; \
  A1 = rotl32(A1, r); B1 = rotl32(B1, r); C1 = rotl32(C1, r); D1 = rotl32(D1, r); \
  A1 ^= A0; B1 ^= B0; C1 ^= C0; D1 ^= D0; }
#define INJ(c0, c1) { A0 += (c0); B0 += (c0); C0 += (c0); D0 += (c0); \
  A1 += (c1); B1 += (c1); C1 += (c1); D1 += (c1); }
#define INJ1(c1) { A1 += (c1); B1 += (c1); C1 += (c1); D1 += (c1); }
  R4(13) R4(15) R4(26) R4(6)
  INJ(k1, k2 + 1u)
  R4(17) R4(29) R4(16) R4(24)
  INJ(k2, 2u)                    // k0+2 = 2
  R4(13) R4(15) R4(26) R4(6)
  INJ1(k1 + 3u)                  // A0 += k0(0) folds
  R4(17) R4(29) R4(16) R4(24)
  INJ(k1, k2 + 4u)
  R4(13) R4(15) R4(26) R4(6)
  INJ(k2, 5u)                    // k0+5 = 5
#undef R4
#undef INJ
#undef INJ1
  ra = A0 ^ A1;
  rb = B0 ^ B1;
  rc = C0 ^ C1;
  rd = D0 ^ D1;
}

// --- K1: bad bitmap + histograms + output padding prefill ---
__global__ void k_build(const int* __restrict__ src, const int* __restrict__ dst,
                        u32* __restrict__ bad, u32* __restrict__ cnt_dst,
                        u32* __restrict__ cnt_src, int* __restrict__ out) {
  int tid = blockIdx.x * 256 + threadIdx.x;   // < 8192
  if (tid < N_CNT) {
    atomicOr(&bad[(u32)tid * NODE_BM_WORDS + ((u32)tid >> 5)], 1u << (tid & 31));
  }
  u32 s = (u32)src[tid], d = (u32)dst[tid];
  atomicOr(&bad[s * NODE_BM_WORDS + (d >> 5)], 1u << (d & 31));
  atomicAdd(&cnt_dst[d], 1u);
  atomicAdd(&cnt_src[s], 1u);
  // prefill: nonzero fill_value=0 -> flat idx 0 -> (src[0], dst[0])
  int s0 = src[0], d0 = dst[0];
  out[tid] = s0;            out[tid + E_CNT] = s0;
  out[OUT_K + tid] = d0;    out[OUT_K + tid + E_CNT] = d0;
}

// --- K2: num_negatives + fused threshold epilogue (last-block-done) ---
// one row per wave (coalesced); block LDS reduce -> 256 atomics total
__global__ void __launch_bounds__(1024) k_rowcount(const u32* __restrict__ bad,
                                                   const u32* __restrict__ cnt_dst,
                                                   const u32* __restrict__ cnt_src,
                                                   u32* __restrict__ scal) {
  int wv = threadIdx.x >> 6, ln = threadIdx.x & 63;
  int n = blockIdx.x * 16 + wv;                 // 256 blocks x 16 waves = 4096 rows
  const u32* row = bad + (u32)n * NODE_BM_WORDS;
  u32 sum = 0;
#pragma unroll
  for (int h = 0; h < 2; ++h) {
    int w = ln + h * 64;
    u32 bits = row[w];
    while (bits) { int b = __ffs(bits) - 1; sum += cnt_dst[(w << 5) + b]; bits &= bits - 1; }
  }
#pragma unroll
  for (int off = 32; off > 0; off >>= 1) sum += __shfl_down(sum, off, 64);
  __shared__ u32 part[16];
  if (ln == 0) part[wv] = ((u32)E_CNT - sum) * cnt_src[n];
  __syncthreads();
  if (threadIdx.x == 0) {
    u32 tot = 0;
#pragma unroll
    for (int k = 0; k < 16; ++k) tot += part[k];
    atomicAdd(&scal[0], tot);
    __threadfence();
    if (atomicAdd(&scal[1], 1u) == 255u) {      // last of 256 blocks
      u32 nn = atomicAdd(&scal[0], 0u);         // coherent read
      u32 ratio = nn >> 13;                     // num_neg // E
      float kp = 2.0f / (float)ratio;           // f32(K)/f32(ratio), as JAX
      // u = m*2^-23 exact; u < kp  <=>  m < T = ceil(kp*2^23)  <=>  bits < T<<9
      u32 T = (u32)ceil((double)kp * 8388608.0);
      u32 T9 = (T >= (1u << 23)) ? 0xFFFFFFFFu : (T << 9);
      atomicExch(&scal[2], T9);
    }
  }
}

// --- K3: partitionable threefry, ballot packing (verified 125us structure).
// ONLY change vs the verified version: 1024-thread blocks (grid 32768->8192)
// to test the WG-dispatch/ramp theory. Per-wave code is byte-identical.
__global__ void __launch_bounds__(1024) k_sample(const int* __restrict__ src,
                                                 const int* __restrict__ dst,
                                                 const u32* __restrict__ bad,
                                                 const u32* __restrict__ scal,
                                                 u64* __restrict__ keep_bm,
                                                 u32* __restrict__ ccount) {
  u32 wv = threadIdx.x >> 6, ln = threadIdx.x & 63;
  u32 i0w = blockIdx.x * 8192u + wv * 512u;     // 16 waves/block, 512 elems/wave
  u32 T9 = scal[2];
  u64 words[8];
  u64 any = 0;
#pragma unroll
  for (int h = 0; h < 2; ++h) {                 // h -> elements k=4h..4h+3
    u32 i0 = i0w + (u32)h * 256u + ln;
    u32 b0, b1, b2, b3;
    threefry4_0_42(i0, i0 + 64u, i0 + 128u, i0 + 192u, b0, b1, b2, b3);
    u64 m0 = __ballot(b0 < T9);
    u64 m1 = __ballot(b1 < T9);
    u64 m2 = __ballot(b2 < T9);
    u64 m3 = __ballot(b3 < T9);
    words[4 * h]     = m0;
    words[4 * h + 1] = m1;
    words[4 * h + 2] = m2;
    words[4 * h + 3] = m3;
    any |= m0 | m1 | m2 | m3;
  }
  if (any) {  // rare (~12% of waves): refine kept lanes against bad bitmap
#pragma unroll
    for (int k = 0; k < 8; ++k) {
      if (words[k]) {
        u32 i = i0w + (u32)k * 64u + ln;
        bool kp = (words[k] >> ln) & 1ull;
        if (kp) {
          u32 n = (u32)src[i >> 13]; u32 v = (u32)dst[i & 8191];
          kp = ((bad[n * NODE_BM_WORDS + (v >> 5)] >> (v & 31)) & 1u) == 0u;
        }
        words[k] = __ballot(kp);
      }
    }
  }
  if (ln == 0) {
    u32 widx = i0w >> 6;                        // multiple of 8 -> 64B aligned
    ulonglong2* p = (ulonglong2*)&keep_bm[widx];
    p[0] = make_ulonglong2(words[0], words[1]);
    p[1] = make_ulonglong2(words[2], words[3]);
    p[2] = make_ulonglong2(words[4], words[5]);
    p[3] = make_ulonglong2(words[6], words[7]);
    u32 c = 0;
#pragma unroll
    for (int k = 0; k < 8; ++k) c += (u32)__popcll(words[k]);
    if (c) atomicAdd(&ccount[i0w >> 16], c);    // chunk uniform per wave
  }
}

// --- K4: ordered compaction; wave-shuffle scans (2 barriers, not 32) ---
__global__ void k_compact(const int* __restrict__ src, const int* __restrict__ dst,
                          const u64* __restrict__ keep_bm, const u32* __restrict__ ccount,
                          int* __restrict__ out) {
  int c = blockIdx.x;                       // chunk id, 1024 u64 words each
  int t = threadIdx.x;                      // 256 threads
  int wvid = t >> 6, ln = t & 63;
  __shared__ u32 red[4];                    // per-wave partial sums (chunk base)
  __shared__ u32 wsum[4];                   // per-wave scan totals (rank scan)

  // ---- chunk base: reduce ccount[0..c-1] (only a sum is needed, not a scan) ----
  u32 part = 0;
#pragma unroll
  for (int k = 0; k < 4; ++k) {
    int q = t + k * 256;                    // q < 1024, always in-bounds
    u32 vq = ccount[q];
    part += (q < c) ? vq : 0u;
  }
  u32 r = part;
#pragma unroll
  for (int off = 32; off > 0; off >>= 1) r += __shfl_down(r, off, 64);
  if (ln == 0) red[wvid] = r;

  // ---- local popcounts (overlap loads with the reduce above) ----
  const u64* words = keep_bm + (size_t)c * 1024;
  u64 w[4];
  u32 cnt = 0;
#pragma unroll
  for (int k = 0; k < 4; ++k) { w[k] = words[4 * t + k]; cnt += (u32)__popcll(w[k]); }

  // ---- rank scan: wave-level inclusive shuffle scan + cross-wave combine ----
  u32 scan = cnt;
#pragma unroll
  for (int off = 1; off < 64; off <<= 1) {
    u32 x = __shfl_up(scan, off, 64);
    if (ln >= off) scan += x;
  }
  if (ln == 63) wsum[wvid] = scan;
  __syncthreads();
  u32 coff_c = red[0] + red[1] + red[2] + red[3];
  u32 wbase = 0;
#pragma unroll
  for (int k = 0; k < 4; ++k) wbase += (k < wvid) ? wsum[k] : 0u;

  u32 rank = coff_c + wbase + scan - cnt;   // global rank of my first set bit
  u32 tbase = (u32)c * 65536u + (u32)t * 256u;
#pragma unroll
  for (int k = 0; k < 4; ++k) {
    u64 bits = w[k];
    while (bits) {
      int b = __ffsll((unsigned long long)bits) - 1;
      if (rank < OUT_K) {
        u32 tt = tbase + (u32)k * 64u + (u32)b;
        out[rank]         = src[tt >> 13];   // edge_src[rows]
        out[OUT_K + rank] = dst[tt & 8191];  // edge_dst[cols]
      }
      rank++;
      bits &= bits - 1;
    }
  }
}

extern "C" void kernel_launch(void* const* d_in, const int* in_sizes, int n_in,
                              void* d_out, int out_size, void* d_ws, size_t ws_size,
                              hipStream_t stream) {
  const int* src = (const int*)d_in[1];  // edge_src
  const int* dst = (const int*)d_in[2];  // edge_dst  (node_feature d_in[0] unused)
  int* out = (int*)d_out;                // [edge_src_neg(16384) | edge_dst_neg(16384)]
  char* ws = (char*)d_ws;

  u32* bad     = (u32*)(ws + OFF_BAD);
  u32* cnt_dst = (u32*)(ws + OFF_CNT_DST);
  u32* cnt_src = (u32*)(ws + OFF_CNT_SRC);
  u32* ccount  = (u32*)(ws + OFF_CCOUNT);
  u32* scal    = (u32*)(ws + OFF_SCALARS);
  u64* keep_bm = (u64*)(ws + OFF_KEEPBM);

  hipMemsetAsync(ws, 0, ZERO_BYTES, stream);
  k_build<<<E_CNT / 256, 256, 0, stream>>>(src, dst, bad, cnt_dst, cnt_src, out);
  k_rowcount<<<N_CNT / 16, 1024, 0, stream>>>(bad, cnt_dst, cnt_src, scal);
  k_sample<<<TOT_N / 8192, 1024, 0, stream>>>(src, dst, bad, scal, keep_bm, ccount);
  k_compact<<<N_CHUNKS, 256, 0, stream>>>(src, dst, keep_bm, ccount, out);
}